// Round 6
// baseline (260.505 us; speedup 1.0000x reference)
//
#include <hip/hip_runtime.h>
#include <hip/hip_bf16.h>
#include <math.h>

typedef unsigned short u16;
typedef __attribute__((ext_vector_type(8))) short short8;
typedef __attribute__((ext_vector_type(4))) float floatx4;

constexpr int kN   = 1024;
constexpr int kB   = 256;
constexpr int kE   = 8192;
constexpr int kHD  = 20;
constexpr float kEps = 1e-5f;

static __device__ __forceinline__ float u16_bf16_to_f32(u16 v) {
  return __uint_as_float(((unsigned)v) << 16);
}
static __device__ __forceinline__ void unpack2(unsigned u, float& a, float& b) {
  a = __uint_as_float(u << 16);
  b = __uint_as_float(u & 0xffff0000u);
}
static __device__ __forceinline__ u16 f2bf(float f) {
  __hip_bfloat16 h = __float2bfloat16(f);
  return *reinterpret_cast<u16*>(&h);
}
static __device__ __forceinline__ unsigned pack_bf16(float a, float b) {
  return (unsigned)f2bf(a) | ((unsigned)f2bf(b) << 16);
}

// per-block dtype detect (bf16 vs fp32) from first 64 words of x
static __device__ __forceinline__ int detect_flag(const unsigned* __restrict__ x) {
  __shared__ int sflag;
  int t = threadIdx.x;
  if (t < 64) {
    unsigned w = x[t];
    unsigned e = (w >> 7) & 0xFFu;
    unsigned long long bl = __ballot(e >= 114u && e <= 136u);
    if (t == 0) sflag = (__popcll(bl) >= 32) ? 1 : 0;
  }
  __syncthreads();
  return sflag;
}

// b-tiled gather layout: row(n, b) = ((b>>6)*kN + n)*64 + (b&63), 20 bf16 per row
static __device__ __forceinline__ size_t gidx(int n, int b) {
  return ((size_t)(b >> 6) * kN + n) * 64 + (b & 63);
}

// ---------------- prep ----------------
struct SmallConv {
  const void* src[17];
  float* dst[17];
  int n[17];
};

struct PrepArgs {
  const unsigned* x;
  const int* ei;
  const void* W1; const void* W2; const void* Wout;
  SmallConv sc;
  u16* xb;      // x transposed -> [N,B,8] bf16
  u16* W1p; u16* W2p; u16* Woutp;
  int* csr_off; int* csr_src;
  float* sums;  // 640 floats zeroed (sums0+sums1)
};

static __device__ __forceinline__ void repack_one(const void* src, u16* dst, int c, int N, int srcbf) {
  int n = c % N;
  int t2 = c / N;
  int q = t2 & 3, kb = t2 >> 2;
  int k0 = kb * 32 + q * 8;
  u16 w[8];
  if (srcbf) {
    const u16* s = (const u16*)src;
#pragma unroll
    for (int j = 0; j < 8; j++) w[j] = s[(size_t)(k0 + j) * N + n];
  } else {
    const float* s = (const float*)src;
#pragma unroll
    for (int j = 0; j < 8; j++) w[j] = f2bf(s[(size_t)(k0 + j) * N + n]);
  }
  uint4 out;
  out.x = (unsigned)w[0] | ((unsigned)w[1] << 16);
  out.y = (unsigned)w[2] | ((unsigned)w[3] << 16);
  out.z = (unsigned)w[4] | ((unsigned)w[5] << 16);
  out.w = (unsigned)w[6] | ((unsigned)w[7] << 16);
  *((uint4*)(dst + (size_t)c * 8)) = out;
}

__global__ __launch_bounds__(256) void prep_kernel(PrepArgs pa) {
  int bid = blockIdx.x;
  int t = threadIdx.x;
  if (bid == 0) {
    // CSR build (one block)
    __shared__ int cnt[kN];
    __shared__ int cur[kN];
    __shared__ int wsum[4];
    for (int i = t; i < kN; i += 256) cnt[i] = 0;
    __syncthreads();
    for (int e = t; e < kE; e += 256) atomicAdd(&cnt[pa.ei[kE + e]], 1);
    __syncthreads();
    int d[4], pre[4];
    int s = 0;
#pragma unroll
    for (int j = 0; j < 4; j++) { d[j] = cnt[t * 4 + j] + 1; pre[j] = s; s += d[j]; }
    int lane = t & 63;
    int v = s;
    for (int o = 1; o < 64; o <<= 1) { int u = __shfl_up(v, o); if (lane >= o) v += u; }
    if (lane == 63) wsum[t >> 6] = v;
    __syncthreads();
    int wbase = 0;
    for (int w = 0; w < (t >> 6); w++) wbase += wsum[w];
    int base = wbase + v - s;
#pragma unroll
    for (int j = 0; j < 4; j++) {
      pa.csr_off[t * 4 + j] = base + pre[j];
      cur[t * 4 + j] = base + pre[j];
    }
    if (t == 255) pa.csr_off[kN] = wbase + v;
    __syncthreads();
    for (int e = t; e < kE; e += 256) {
      int sv = pa.ei[e], dv = pa.ei[kE + e];
      int pos = atomicAdd(&cur[dv], 1);
      pa.csr_src[pos] = sv;
    }
    for (int i = t; i < kN; i += 256) {
      int pos = atomicAdd(&cur[i], 1);
      pa.csr_src[pos] = i;
    }
    return;
  }
  int flag = detect_flag(pa.x);
  if (bid == 1) {
    for (int i = t; i < 640; i += 256) pa.sums[i] = 0.f;
    for (int k = 0; k < 17; k++) {
      int n = pa.sc.n[k];
      float* d = pa.sc.dst[k];
      if (flag) {
        const u16* s = (const u16*)pa.sc.src[k];
        for (int i = t; i < n; i += 256) d[i] = u16_bf16_to_f32(s[i]);
      } else {
        const float* s = (const float*)pa.sc.src[k];
        for (int i = t; i < n; i += 256) d[i] = s[i];
      }
    }
    return;
  }
  if (bid < 158) {
    int c = (bid - 2) * 256 + t;
    if (c < 34816) repack_one(pa.W1, pa.W1p, c, 256, flag);
    else if (c < 34816 + 4096) repack_one(pa.W2, pa.W2p, c - 34816, 128, flag);
    else if (c < 34816 + 4096 + 1024) repack_one(pa.Wout, pa.Woutp, c - 34816 - 4096, 64, flag);
    return;
  }
  // x [B,N,8] -> xb [N,B,8] bf16 (coalesced reads)
  int rid = (bid - 158) * 256 + t;  // b*1024+n
  int b = rid >> 10, n = rid & 1023;
  uint4 o;
  if (flag) {
    o = *((const uint4*)((const u16*)pa.x + (size_t)rid * 8));
  } else {
    const float4* s = (const float4*)((const float*)pa.x + (size_t)rid * 8);
    float4 r0 = s[0], r1 = s[1];
    o.x = pack_bf16(r0.x, r0.y); o.y = pack_bf16(r0.z, r0.w);
    o.z = pack_bf16(r1.x, r1.y); o.w = pack_bf16(r1.z, r1.w);
  }
  *((uint4*)(pa.xb + ((size_t)n * kB + b) * 8)) = o;
}

// ---------------- layer 0 left-linear: xb[N,B,8] -> xl (b-tiled) ----------------
__global__ __launch_bounds__(256) void lin0_kernel(const u16* __restrict__ xb,
                                                   const float* __restrict__ Wl,
                                                   u16* __restrict__ xlb) {
  __shared__ float wl[160];
  int t = threadIdx.x;
  if (t < 160) wl[t] = Wl[t];
  __syncthreads();
  int n = blockIdx.x, b = t;
  uint4 r = *((const uint4*)(xb + ((size_t)n * kB + b) * 8));
  float xi[8];
  unpack2(r.x, xi[0], xi[1]); unpack2(r.y, xi[2], xi[3]);
  unpack2(r.z, xi[4], xi[5]); unpack2(r.w, xi[6], xi[7]);
  float ol[kHD];
#pragma unroll
  for (int f = 0; f < kHD; f++) {
    float al = 0.f;
#pragma unroll
    for (int i = 0; i < 8; i++) al = fmaf(xi[i], wl[i * kHD + f], al);
    ol[f] = al;
  }
  uint2* pl = (uint2*)(xlb + gidx(n, b) * kHD);
#pragma unroll
  for (int k = 0; k < 5; k++)
    pl[k] = make_uint2(pack_bf16(ol[4 * k], ol[4 * k + 1]), pack_bf16(ol[4 * k + 2], ol[4 * k + 3]));
}

// ---------------- layer 1 left-linear (BN0 fold inlined): hb -> xl ----------------
__global__ __launch_bounds__(256) void lin1_kernel(const u16* __restrict__ hb,
                                                   const float* __restrict__ sums0,
                                                   const float* __restrict__ g0,
                                                   const float* __restrict__ be0,
                                                   const float* __restrict__ Wl1,
                                                   u16* __restrict__ xlb) {
  __shared__ float wl[400], sbl[kHD], afold[kHD], cfold[kHD], tot[2 * kHD];
  int t = threadIdx.x;
  if (t < 2 * kHD) {
    float v = 0.f;
    for (int k = 0; k < 8; k++) v += sums0[k * 2 * kHD + t];
    tot[t] = v;
  }
  __syncthreads();
  if (t < kHD) {
    const float inv = 1.0f / (float)(kN * kB);
    float mu = tot[t] * inv;
    float var = tot[kHD + t] * inv - mu * mu;
    float a = g0[t] * rsqrtf(var + kEps);
    afold[t] = a;
    cfold[t] = be0[t] - mu * a;
  }
  __syncthreads();
  for (int idx = t; idx < 400; idx += 256) wl[idx] = afold[idx / kHD] * Wl1[idx];
  if (t < kHD) {
    float s = 0.f;
    for (int f = 0; f < kHD; f++) s += cfold[f] * Wl1[f * kHD + t];
    sbl[t] = s;
  }
  __syncthreads();
  int n = blockIdx.x, b = t;
  float hv[kHD];
  {
    const uint2* p = (const uint2*)(hb + gidx(n, b) * kHD);
#pragma unroll
    for (int k = 0; k < 5; k++) {
      uint2 v = p[k];
      unpack2(v.x, hv[4 * k], hv[4 * k + 1]);
      unpack2(v.y, hv[4 * k + 2], hv[4 * k + 3]);
    }
  }
  float ol[kHD];
#pragma unroll
  for (int j = 0; j < kHD; j++) {
    float al = sbl[j];
#pragma unroll
    for (int f = 0; f < kHD; f++) al = fmaf(hv[f], wl[f * kHD + j], al);
    ol[j] = al;
  }
  uint2* pl = (uint2*)(xlb + gidx(n, b) * kHD);
#pragma unroll
  for (int k = 0; k < 5; k++)
    pl[k] = make_uint2(pack_bf16(ol[4 * k], ol[4 * k + 1]), pack_bf16(ol[4 * k + 2], ol[4 * k + 3]));
}

// ---------------- attn layer 0: 64-thread blocks, tile = bid&3 (XCD L2 affinity) ----------------
__global__ __launch_bounds__(64) void attn0_kernel(const u16* __restrict__ xlb,
                                                   const u16* __restrict__ xb,
                                                   const float* __restrict__ Wr0,
                                                   const float* __restrict__ att,
                                                   const float* __restrict__ bias,
                                                   const int* __restrict__ csr_off,
                                                   const int* __restrict__ csr_src,
                                                   u16* __restrict__ hout,
                                                   float* __restrict__ sums) {
  __shared__ float satt[kHD], sbias[kHD], swr[160];
  __shared__ int ssrc[128];
  __shared__ float red[2 * kHD];
  int t = threadIdx.x;
  int tb = blockIdx.x & 3;
  int n = blockIdx.x >> 2;
  if (t < kHD) { satt[t] = att[t]; sbias[t] = bias[t]; }
  for (int i = t; i < 160; i += 64) swr[i] = Wr0[i];
  int beg = csr_off[n], end = csr_off[n + 1];
  int deg = end - beg;
  for (int i = t; i < deg && i < 128; i += 64) ssrc[i] = csr_src[beg + i];
  __syncthreads();
  int b = (tb << 6) | t;
  float xrv[kHD];
  {
    uint4 r = *((const uint4*)(xb + ((size_t)n * kB + b) * 8));
    float xi[8];
    unpack2(r.x, xi[0], xi[1]); unpack2(r.y, xi[2], xi[3]);
    unpack2(r.z, xi[4], xi[5]); unpack2(r.w, xi[6], xi[7]);
#pragma unroll
    for (int f = 0; f < kHD; f++) {
      float a = 0.f;
#pragma unroll
      for (int i = 0; i < 8; i++) a = fmaf(xi[i], swr[i * kHD + f], a);
      xrv[f] = a;
    }
  }
  float s[4] = {0.f, 0.f, 0.f, 0.f};
  float acc[kHD];
#pragma unroll
  for (int f = 0; f < kHD; f++) acc[f] = 0.f;

  const size_t tilebase = (size_t)tb * kN * 64 * kHD;
  auto loadrow = [&](int i, uint2 (&rr)[5]) {
    int srcn = (i < 128) ? ssrc[i] : csr_src[beg + i];
    const uint2* p = (const uint2*)(xlb + tilebase + ((size_t)srcn * 64 + t) * kHD);
#pragma unroll
    for (int k = 0; k < 5; k++) rr[k] = p[k];
  };
  auto consume = [&](uint2 (&rr)[5]) {
    float xs[kHD];
#pragma unroll
    for (int k = 0; k < 5; k++) {
      unpack2(rr[k].x, xs[4 * k], xs[4 * k + 1]);
      unpack2(rr[k].y, xs[4 * k + 2], xs[4 * k + 3]);
    }
#pragma unroll
    for (int hh = 0; hh < 4; hh++) {
      float e = 0.f;
#pragma unroll
      for (int d2 = 0; d2 < 5; d2++) {
        int f = hh * 5 + d2;
        float v = xs[f] + xrv[f];
        v = fmaxf(v, 0.2f * v);
        e = fmaf(v, satt[f], e);
      }
      float p = __expf(e);
      s[hh] += p;
#pragma unroll
      for (int d2 = 0; d2 < 5; d2++) {
        int f = hh * 5 + d2;
        acc[f] = fmaf(p, xs[f], acc[f]);
      }
    }
  };

  uint2 r0[5], r1[5];
  loadrow(0, r0);
  if (deg > 1) loadrow(1, r1);
  int i = 0;
  for (; i + 1 < deg; i += 2) {
    consume(r0);
    if (i + 2 < deg) loadrow(i + 2, r0);
    consume(r1);
    if (i + 3 < deg) loadrow(i + 3, r1);
  }
  if (i < deg) consume(r0);

  float hv[kHD];
#pragma unroll
  for (int hh = 0; hh < 4; hh++) {
    float inv = 1.f / s[hh];
#pragma unroll
    for (int d2 = 0; d2 < 5; d2++) {
      int f = hh * 5 + d2;
      hv[f] = fmaf(acc[f], inv, sbias[f]);
    }
  }
  {
    uint2* ph = (uint2*)(hout + tilebase + ((size_t)n * 64 + t) * kHD);
#pragma unroll
    for (int k = 0; k < 5; k++)
      ph[k] = make_uint2(pack_bf16(hv[4 * k], hv[4 * k + 1]), pack_bf16(hv[4 * k + 2], hv[4 * k + 3]));
  }
  // BN0 stats (wave reduce)
#pragma unroll
  for (int f = 0; f < kHD; f++) {
    float a = hv[f], q = hv[f] * hv[f];
    for (int o = 32; o > 0; o >>= 1) { a += __shfl_down(a, o); q += __shfl_down(q, o); }
    if (t == 0) { red[f] = a; red[kHD + f] = q; }
  }
  __syncthreads();
  if (t < 2 * kHD) atomicAdd(&sums[(blockIdx.x & 7) * 2 * kHD + t], red[t]);
}

// ---------------- attn layer 1 (BN0 fold inlined for xr; no stats) ----------------
__global__ __launch_bounds__(64) void attn1_kernel(const u16* __restrict__ xlb,
                                                   const u16* __restrict__ hb,
                                                   const float* __restrict__ sums0,
                                                   const float* __restrict__ g0,
                                                   const float* __restrict__ be0,
                                                   const float* __restrict__ Wr1,
                                                   const float* __restrict__ att,
                                                   const float* __restrict__ bias,
                                                   const int* __restrict__ csr_off,
                                                   const int* __restrict__ csr_src,
                                                   u16* __restrict__ hout) {
  __shared__ float satt[kHD], sbias[kHD], swr[400], sbr[kHD];
  __shared__ float afold[kHD], cfold[kHD], tot[2 * kHD];
  __shared__ int ssrc[128];
  int t = threadIdx.x;
  int tb = blockIdx.x & 3;
  int n = blockIdx.x >> 2;
  if (t < kHD) { satt[t] = att[t]; sbias[t] = bias[t]; }
  if (t < 2 * kHD) {
    float v = 0.f;
    for (int k = 0; k < 8; k++) v += sums0[k * 2 * kHD + t];
    tot[t] = v;
  }
  int beg = csr_off[n], end = csr_off[n + 1];
  int deg = end - beg;
  for (int i = t; i < deg && i < 128; i += 64) ssrc[i] = csr_src[beg + i];
  __syncthreads();
  if (t < kHD) {
    const float inv = 1.0f / (float)(kN * kB);
    float mu = tot[t] * inv;
    float var = tot[kHD + t] * inv - mu * mu;
    float a = g0[t] * rsqrtf(var + kEps);
    afold[t] = a;
    cfold[t] = be0[t] - mu * a;
  }
  __syncthreads();
  for (int idx = t; idx < 400; idx += 64) swr[idx] = afold[idx / kHD] * Wr1[idx];
  if (t < kHD) {
    float sv = 0.f;
    for (int f = 0; f < kHD; f++) sv = fmaf(cfold[f], Wr1[f * kHD + t], sv);
    sbr[t] = sv;
  }
  __syncthreads();
  const size_t tilebase = (size_t)tb * kN * 64 * kHD;
  float xrv[kHD];
  {
    float hv0[kHD];
    const uint2* p = (const uint2*)(hb + tilebase + ((size_t)n * 64 + t) * kHD);
#pragma unroll
    for (int k = 0; k < 5; k++) {
      uint2 v = p[k];
      unpack2(v.x, hv0[4 * k], hv0[4 * k + 1]);
      unpack2(v.y, hv0[4 * k + 2], hv0[4 * k + 3]);
    }
#pragma unroll
    for (int j = 0; j < kHD; j++) {
      float a = sbr[j];
#pragma unroll
      for (int f = 0; f < kHD; f++) a = fmaf(hv0[f], swr[f * kHD + j], a);
      xrv[j] = a;
    }
  }
  float s[4] = {0.f, 0.f, 0.f, 0.f};
  float acc[kHD];
#pragma unroll
  for (int f = 0; f < kHD; f++) acc[f] = 0.f;

  auto loadrow = [&](int i, uint2 (&rr)[5]) {
    int srcn = (i < 128) ? ssrc[i] : csr_src[beg + i];
    const uint2* p = (const uint2*)(xlb + tilebase + ((size_t)srcn * 64 + t) * kHD);
#pragma unroll
    for (int k = 0; k < 5; k++) rr[k] = p[k];
  };
  auto consume = [&](uint2 (&rr)[5]) {
    float xs[kHD];
#pragma unroll
    for (int k = 0; k < 5; k++) {
      unpack2(rr[k].x, xs[4 * k], xs[4 * k + 1]);
      unpack2(rr[k].y, xs[4 * k + 2], xs[4 * k + 3]);
    }
#pragma unroll
    for (int hh = 0; hh < 4; hh++) {
      float e = 0.f;
#pragma unroll
      for (int d2 = 0; d2 < 5; d2++) {
        int f = hh * 5 + d2;
        float v = xs[f] + xrv[f];
        v = fmaxf(v, 0.2f * v);
        e = fmaf(v, satt[f], e);
      }
      float p = __expf(e);
      s[hh] += p;
#pragma unroll
      for (int d2 = 0; d2 < 5; d2++) {
        int f = hh * 5 + d2;
        acc[f] = fmaf(p, xs[f], acc[f]);
      }
    }
  };

  uint2 r0[5], r1[5];
  loadrow(0, r0);
  if (deg > 1) loadrow(1, r1);
  int i = 0;
  for (; i + 1 < deg; i += 2) {
    consume(r0);
    if (i + 2 < deg) loadrow(i + 2, r0);
    consume(r1);
    if (i + 3 < deg) loadrow(i + 3, r1);
  }
  if (i < deg) consume(r0);

  float hv[kHD];
#pragma unroll
  for (int hh = 0; hh < 4; hh++) {
    float inv = 1.f / s[hh];
#pragma unroll
    for (int d2 = 0; d2 < 5; d2++) {
      int f = hh * 5 + d2;
      hv[f] = fmaf(acc[f], inv, sbias[f]);
    }
  }
  uint2* ph = (uint2*)(hout + tilebase + ((size_t)n * 64 + t) * kHD);
#pragma unroll
  for (int k = 0; k < 5; k++)
    ph[k] = make_uint2(pack_bf16(hv[4 * k], hv[4 * k + 1]), pack_bf16(hv[4 * k + 2], hv[4 * k + 3]));
}

// ---------------- pool partials + BN1 stats (coalesced) ----------------
// grid 64 blocks (tb = bid&3, ch = bid>>2), 64 threads = b-lanes; chunk = 64 nodes
__global__ __launch_bounds__(64) void pool_kernel(const u16* __restrict__ hb2,
                                                  float* __restrict__ pool_part,
                                                  float* __restrict__ sums1) {
  __shared__ float red[2 * kHD];
  int t = threadIdx.x;
  int tb = blockIdx.x & 3;
  int ch = blockIdx.x >> 2;
  const size_t tilebase = (size_t)tb * kN * 64 * kHD;
  float acc[kHD], q[kHD];
#pragma unroll
  for (int f = 0; f < kHD; f++) { acc[f] = 0.f; q[f] = 0.f; }
  for (int j = 0; j < 64; j++) {
    int n = ch * 64 + j;
    const uint2* p = (const uint2*)(hb2 + tilebase + ((size_t)n * 64 + t) * kHD);
#pragma unroll
    for (int k = 0; k < 5; k++) {
      uint2 v = p[k];
      float a0, a1, a2, a3;
      unpack2(v.x, a0, a1); unpack2(v.y, a2, a3);
      acc[4 * k] += a0;     q[4 * k] += a0 * a0;
      acc[4 * k + 1] += a1; q[4 * k + 1] += a1 * a1;
      acc[4 * k + 2] += a2; q[4 * k + 2] += a2 * a2;
      acc[4 * k + 3] += a3; q[4 * k + 3] += a3 * a3;
    }
  }
  int b = tb * 64 + t;
  float4* pp = (float4*)(pool_part + ((size_t)ch * kB + b) * kHD);
#pragma unroll
  for (int k = 0; k < 5; k++)
    pp[k] = make_float4(acc[4 * k], acc[4 * k + 1], acc[4 * k + 2], acc[4 * k + 3]);
  // BN1 stats
#pragma unroll
  for (int f = 0; f < kHD; f++) {
    float a = acc[f], qq = q[f];
    for (int o = 32; o > 0; o >>= 1) { a += __shfl_down(a, o); qq += __shfl_down(qq, o); }
    if (t == 0) { red[f] = a; red[kHD + f] = qq; }
  }
  __syncthreads();
  if (t < 2 * kHD) atomicAdd(&sums1[(blockIdx.x & 7) * 2 * kHD + t], red[t]);
}

// ---------------- fused: pool-reduce + BN1 + agg + obs + MLP (MFMA) -> logits ----------------
__global__ __launch_bounds__(256) void mlp_kernel(const float* __restrict__ pool_part,
                                                  const float* __restrict__ sums1,
                                                  const float* __restrict__ g1,
                                                  const float* __restrict__ be1,
                                                  const float* __restrict__ Wagg,
                                                  const float* __restrict__ bagg,
                                                  const void* __restrict__ obsraw,
                                                  const u16* __restrict__ W1p,
                                                  const u16* __restrict__ W2p,
                                                  const u16* __restrict__ Woutp,
                                                  const float* __restrict__ bh1,
                                                  const float* __restrict__ bh2,
                                                  const float* __restrict__ bout,
                                                  const unsigned* __restrict__ xdet,
                                                  void* __restrict__ outv) {
  __shared__ __align__(16) u16 fins[16][1096];  // stride 1096 -> 2-way LDS aliasing only
  __shared__ __align__(16) u16 h1s[16][264];
  __shared__ __align__(16) u16 h2s[16][136];
  __shared__ float sWagg[1280], pv[16][kHD], a1[kHD], c1[kHD], tot[2 * kHD];
  int flag = detect_flag(xdet);
  int t = threadIdx.x;
  int m0 = blockIdx.x * 16;
  if (t < 2 * kHD) {
    float v = 0.f;
    for (int k = 0; k < 8; k++) v += sums1[k * 2 * kHD + t];
    tot[t] = v;
  }
  for (int idx = t; idx < 1280; idx += 256) sWagg[idx] = Wagg[idx];
  __syncthreads();
  if (t < kHD) {
    const float inv = 1.0f / (float)(kN * kB);
    float mu = tot[t] * inv;
    float var = tot[kHD + t] * inv - mu * mu;
    float a = g1[t] * rsqrtf(var + kEps);
    a1[t] = a;
    c1[t] = be1[t] - mu * a;
  }
  __syncthreads();
  // pool reduce over 16 chunks for this block's 16 batches
  for (int idx = t; idx < 16 * kHD; idx += 256) {
    int bl = idx / kHD, f = idx % kHD;
    float p = 0.f;
    for (int ch = 0; ch < 16; ch++) p += pool_part[((size_t)ch * kB + m0 + bl) * kHD + f];
    pv[bl][f] = (p * (1.0f / kN)) * a1[f] + c1[f];
  }
  // obs -> fins[r][64..1088)
  for (int idx = t * 8; idx < 16 * 1024; idx += 2048) {
    int r = idx >> 10, c = idx & 1023;
    uint4 o;
    if (flag) {
      o = *((const uint4*)((const u16*)obsraw + (size_t)(m0 + r) * 1024 + c));
    } else {
      const float4* sp = (const float4*)((const float*)obsraw + (size_t)(m0 + r) * 1024 + c);
      float4 r0 = sp[0], r1 = sp[1];
      o.x = pack_bf16(r0.x, r0.y); o.y = pack_bf16(r0.z, r0.w);
      o.z = pack_bf16(r1.x, r1.y); o.w = pack_bf16(r1.z, r1.w);
    }
    *(uint4*)&fins[r][64 + c] = o;
  }
  __syncthreads();
  // agg -> fins[r][0..64)
  {
    int j = t & 63, rg = t >> 6;
    for (int r = rg; r < 16; r += 4) {
      float a = bagg[j];
#pragma unroll
      for (int f = 0; f < kHD; f++) a = fmaf(pv[r][f], sWagg[f * 64 + j], a);
      fins[r][j] = f2bf(a);
    }
  }
  __syncthreads();
  int wave = t >> 6, lane = t & 63, lo = lane & 15, quad = lane >> 4;
  // layer 1: h1[16,256]
  {
    floatx4 acc[4] = {{0.f, 0.f, 0.f, 0.f}, {0.f, 0.f, 0.f, 0.f}, {0.f, 0.f, 0.f, 0.f}, {0.f, 0.f, 0.f, 0.f}};
    for (int kb = 0; kb < 34; kb++) {
      short8 a = *(const short8*)&fins[lo][kb * 32 + quad * 8];
#pragma unroll
      for (int nt = 0; nt < 4; nt++) {
        int n0 = (wave * 4 + nt) * 16;
        short8 bf = *(const short8*)(W1p + ((size_t)(kb * 4 + quad) * 256 + n0 + lo) * 8);
        acc[nt] = __builtin_amdgcn_mfma_f32_16x16x32_bf16(a, bf, acc[nt], 0, 0, 0);
      }
    }
#pragma unroll
    for (int nt = 0; nt < 4; nt++) {
      int n0 = (wave * 4 + nt) * 16;
      float bias = bh1[n0 + lo];
#pragma unroll
      for (int r = 0; r < 4; r++) h1s[quad * 4 + r][n0 + lo] = f2bf(tanhf(acc[nt][r] + bias));
    }
  }
  __syncthreads();
  // layer 2: h2[16,128]
  {
    floatx4 acc[2] = {{0.f, 0.f, 0.f, 0.f}, {0.f, 0.f, 0.f, 0.f}};
    for (int kb = 0; kb < 8; kb++) {
      short8 a = *(const short8*)&h1s[lo][kb * 32 + quad * 8];
#pragma unroll
      for (int nt = 0; nt < 2; nt++) {
        int n0 = (wave * 2 + nt) * 16;
        short8 bf = *(const short8*)(W2p + ((size_t)(kb * 4 + quad) * 128 + n0 + lo) * 8);
        acc[nt] = __builtin_amdgcn_mfma_f32_16x16x32_bf16(a, bf, acc[nt], 0, 0, 0);
      }
    }
#pragma unroll
    for (int nt = 0; nt < 2; nt++) {
      int n0 = (wave * 2 + nt) * 16;
      float bias = bh2[n0 + lo];
#pragma unroll
      for (int r = 0; r < 4; r++) h2s[quad * 4 + r][n0 + lo] = f2bf(tanhf(acc[nt][r] + bias));
    }
  }
  __syncthreads();
  // layer 3: out[16,64]
  {
    int n0 = wave * 16;
    floatx4 acc = {0.f, 0.f, 0.f, 0.f};
    for (int kb = 0; kb < 4; kb++) {
      short8 a = *(const short8*)&h2s[lo][kb * 32 + quad * 8];
      short8 bf = *(const short8*)(Woutp + ((size_t)(kb * 4 + quad) * 64 + n0 + lo) * 8);
      acc = __builtin_amdgcn_mfma_f32_16x16x32_bf16(a, bf, acc, 0, 0, 0);
    }
    float bias = bout[n0 + lo];
    if (flag) {
      __hip_bfloat16* o = (__hip_bfloat16*)outv;
#pragma unroll
      for (int r = 0; r < 4; r++)
        o[(size_t)(m0 + quad * 4 + r) * 64 + n0 + lo] = __float2bfloat16(acc[r] + bias);
    } else {
      float* o = (float*)outv;
#pragma unroll
      for (int r = 0; r < 4; r++)
        o[(size_t)(m0 + quad * 4 + r) * 64 + n0 + lo] = acc[r] + bias;
    }
  }
}

// ---------------- launch ----------------
extern "C" void kernel_launch(void* const* d_in, const int* in_sizes, int n_in,
                              void* d_out, int out_size, void* d_ws, size_t ws_size,
                              hipStream_t stream) {
  const int* ei = (const int*)d_in[2];
  char* ws = (char*)d_ws;

  float* sums0     = (float*)(ws + 0);        // 1280
  float* sums1     = (float*)(ws + 1280);     // 1280 -> 2560
  int*   csr_off   = (int*)(ws + 2816);       // 4100
  int*   csr_src   = (int*)(ws + 7168);       // 36864 -> 44032
  float* convf     = (float*)(ws + 44288);    // 3072 floats -> 56576
  u16*   W1p       = (u16*)(ws + 56832);      // 557056 -> 613888
  u16*   W2p       = (u16*)(ws + 613888);     // 65536 -> 679424
  u16*   Woutp     = (u16*)(ws + 679424);     // 16384 -> 695808
  float* pool_part = (float*)(ws + 695808);   // 16*256*20*4 = 327680 -> 1023488
  u16*   xb        = (u16*)(ws + 1023744);    // 4194304 -> 5218048
  u16*   xlb       = (u16*)(ws + 5218048);    // 10485760 -> 15703808
  u16*   hb        = (u16*)(ws + 15703808);   // 10485760 -> 26189568
  u16*   hb2       = (u16*)(ws + 26189568);   // 10485760 -> 36675328

  const int s_din[17] = {3, 4, 5, 6, 7, 8, 9, 10, 11, 12, 13, 14, 15, 16, 18, 20, 22};
  const int s_n[17]   = {160, 160, 20, 20, 400, 400, 20, 20, 20, 20, 20, 20, 1280, 64, 256, 128, 64};
  SmallConv sc;
  float* fptr[17];
  {
    size_t co = 0;
    for (int i = 0; i < 17; i++) {
      sc.src[i] = d_in[s_din[i]];
      sc.dst[i] = convf + co;
      sc.n[i] = s_n[i];
      fptr[i] = convf + co;
      co += (size_t)s_n[i];
    }
  }
  float* Wl0_f = fptr[0],  *Wr0_f = fptr[1],  *att0_f = fptr[2], *b0_f = fptr[3];
  float* Wl1_f = fptr[4],  *Wr1_f = fptr[5],  *att1_f = fptr[6], *b1_f = fptr[7];
  float* g0_f = fptr[8],   *be0_f = fptr[9],  *g1_f = fptr[10],  *be1_f = fptr[11];
  float* Wagg_f = fptr[12], *bagg_f = fptr[13], *bh1_f = fptr[14], *bh2_f = fptr[15];
  float* bout_f = fptr[16];

  PrepArgs pa;
  pa.x = (const unsigned*)d_in[0];
  pa.ei = ei;
  pa.W1 = d_in[17]; pa.W2 = d_in[19]; pa.Wout = d_in[21];
  pa.sc = sc;
  pa.xb = xb;
  pa.W1p = W1p; pa.W2p = W2p; pa.Woutp = Woutp;
  pa.csr_off = csr_off; pa.csr_src = csr_src;
  pa.sums = sums0;

  prep_kernel<<<1182, 256, 0, stream>>>(pa);
  lin0_kernel<<<kN, 256, 0, stream>>>(xb, Wl0_f, xlb);
  attn0_kernel<<<4 * kN, 64, 0, stream>>>(xlb, xb, Wr0_f, att0_f, b0_f, csr_off, csr_src, hb, sums0);
  lin1_kernel<<<kN, 256, 0, stream>>>(hb, sums0, g0_f, be0_f, Wl1_f, xlb);
  attn1_kernel<<<4 * kN, 64, 0, stream>>>(xlb, hb, sums0, g0_f, be0_f, Wr1_f, att1_f, b1_f,
                                          csr_off, csr_src, hb2);
  pool_kernel<<<64, 64, 0, stream>>>(hb2, pool_part, sums1);
  mlp_kernel<<<16, 256, 0, stream>>>(pool_part, sums1, g1_f, be1_f, Wagg_f, bagg_f, d_in[1],
                                     W1p, W2p, Woutp, bh1_f, bh2_f, bout_f,
                                     (const unsigned*)d_in[0], d_out);
}